// Round 13
// baseline (637.279 us; speedup 1.0000x reference)
//
#include <hip/hip_runtime.h>
#include <hip/hip_cooperative_groups.h>
#include <cstdint>

namespace cg = cooperative_groups;

#define N_NODES 50000
#define N_EDGES 800000
#define E_TOT   (N_EDGES + N_NODES)   // 850000 with self-loops
#define IN_CH   128
#define HEADS   8
#define CCH     32
#define HC      256                    // HEADS*CCH
#define OUTC    64
#define COOP_BLOCKS 1024
#define NSCANB  196                    // 196*256 = 50176 >= N_NODES

typedef unsigned short ushort_t;
typedef __attribute__((ext_vector_type(8))) short bf16x8;
typedef __attribute__((ext_vector_type(8))) unsigned short u16x8;
typedef __attribute__((ext_vector_type(4))) float f32x4;

// bf16 helpers (RNE rounding on pack)
static __device__ __forceinline__ unsigned short f2bf(float f) {
    unsigned u = __float_as_uint(f);
    u = u + 0x7fffu + ((u >> 16) & 1u);
    return (unsigned short)(u >> 16);
}
static __device__ __forceinline__ float bf2f(unsigned short h) {
    return __uint_as_float((unsigned)h << 16);
}
static __device__ __forceinline__ unsigned pack2(float lo, float hi) {
    return (unsigned)f2bf(lo) | ((unsigned)f2bf(hi) << 16);
}
static __device__ __forceinline__ float lrexp(float v) {
    v = v > 0.f ? v : 0.2f * v;        // LeakyReLU(0.2)
    return expf(v);
}
static __device__ __forceinline__ bf16x8 cvt8(float4 lo, float4 hi) {
    bf16x8 r;
    r[0] = (short)f2bf(lo.x); r[1] = (short)f2bf(lo.y);
    r[2] = (short)f2bf(lo.z); r[3] = (short)f2bf(lo.w);
    r[4] = (short)f2bf(hi.x); r[5] = (short)f2bf(hi.y);
    r[6] = (short)f2bf(hi.z); r[7] = (short)f2bf(hi.w);
    return r;
}

// ===== ONE cooperative kernel: repack + memset + hist + scan + scatter ======
__global__ __launch_bounds__(256) void csr_coop(
        const int* __restrict__ ei,
        const float* __restrict__ W1, const float* __restrict__ W2,
        ushort_t* __restrict__ W1f, ushort_t* __restrict__ W2f,
        int* __restrict__ deg, int* __restrict__ inc, int* __restrict__ bsum,
        int* __restrict__ rowstart, int* __restrict__ cursor,
        int* __restrict__ col) {
    cg::grid_group grid = cg::this_grid();
    __shared__ int sh[256];
    __shared__ int pref[NSCANB];
    const int tid = blockIdx.x * 256 + threadIdx.x;
    const int nth = COOP_BLOCKS * 256;

    // phase 0: zero deg + repack weights to MFMA fragment order
    for (int i = tid; i < N_NODES; i += nth) deg[i] = 0;
    if (tid < 32768) {
        int j = tid & 7, lane = (tid >> 3) & 63, f = tid >> 9;
        int nt = f >> 2, kk = f & 3;
        int k = kk * 32 + (lane >> 4) * 8 + j;
        int n = (nt >> 1) * 32 + 2 * (lane & 15) + (nt & 1);
        W1f[tid] = f2bf(W1[k * HC + n]);
    } else if (tid < 32768 + 16384) {
        int u = tid - 32768;
        int j = u & 7, lane = (u >> 3) & 63, f = u >> 9;
        int nt = f >> 3, kk = f & 7;
        int k = kk * 32 + (lane >> 4) * 8 + j;
        int n = (nt >> 1) * 32 + 2 * (lane & 15) + (nt & 1);
        W2f[u] = f2bf(W2[k * OUTC + n]);
    }
    grid.sync();

    // phase 1: degree histogram
    for (int e = tid; e < E_TOT; e += nth) {
        int dv = (e < N_EDGES) ? ei[N_EDGES + e] : (e - N_EDGES);
        atomicAdd(&deg[dv], 1);
    }
    grid.sync();

    // phase 2a: 256-wide block-scan of deg (blocks 0..NSCANB-1)
    if (blockIdx.x < NSCANB) {
        int i = blockIdx.x * 256 + threadIdx.x;
        sh[threadIdx.x] = (i < N_NODES) ? deg[i] : 0;
        __syncthreads();
        for (int o = 1; o < 256; o <<= 1) {
            int t = (threadIdx.x >= o) ? sh[threadIdx.x - o] : 0;
            __syncthreads();
            sh[threadIdx.x] += t;
            __syncthreads();
        }
        if (i < N_NODES) inc[i] = sh[threadIdx.x];
        if (threadIdx.x == 255) bsum[blockIdx.x] = sh[255];
    }
    grid.sync();

    // phase 2b: finalize rowstart/cursor (blocks 0..NSCANB-1, redundant prefix)
    if (blockIdx.x < NSCANB) {
        if (threadIdx.x == 0) {
            int acc = 0;
            for (int k = 0; k < NSCANB; ++k) { pref[k] = acc; acc += bsum[k]; }
        }
        __syncthreads();
        int i = blockIdx.x * 256 + threadIdx.x;
        if (i < N_NODES) {
            int v = inc[i] + pref[blockIdx.x];
            rowstart[i + 1] = v;
            if (i + 1 < N_NODES) cursor[i + 1] = v;
            if (i == 0) { rowstart[0] = 0; cursor[0] = 0; }
        }
    }
    grid.sync();

    // phase 3: scatter src ids into CSR order
    for (int e = tid; e < E_TOT; e += nth) {
        int sv, dv;
        if (e < N_EDGES) { sv = ei[e]; dv = ei[N_EDGES + e]; }
        else             { sv = dv = e - N_EDGES; }
        int pos = atomicAdd(&cursor[dv], 1);
        col[pos] = sv;
    }
}

// ====== Layer 1 MFMA GEMM + fused logits: h1b(bf16), al1, ar1 ===============
__global__ __launch_bounds__(256) void gemm1_mfma(
        const float* __restrict__ x, const ushort_t* __restrict__ W1f,
        const float* __restrict__ a_src, const float* __restrict__ a_dst,
        ushort_t* __restrict__ h1b, float* __restrict__ al, float* __restrict__ ar) {
    const int lane = threadIdx.x & 63;
    const int wv   = threadIdx.x >> 6;
    const int base = blockIdx.x * 64 + wv * 16;
    if (base >= N_NODES) return;
    const int am = base + (lane & 15);
    const int rm = am < N_NODES ? am : N_NODES - 1;

    bf16x8 a[4];
    const float* xr = &x[(size_t)rm * IN_CH + (lane >> 4) * 8];
    #pragma unroll
    for (int kk = 0; kk < 4; ++kk) {
        float4 lo = *(const float4*)&xr[kk * 32];
        float4 hi = *(const float4*)&xr[kk * 32 + 4];
        a[kk] = cvt8(lo, hi);
    }

    f32x4 acc[16];
    #pragma unroll
    for (int nt = 0; nt < 16; ++nt) acc[nt] = (f32x4){0.f, 0.f, 0.f, 0.f};

    const bf16x8* bp = (const bf16x8*)W1f;
    #pragma unroll
    for (int nt = 0; nt < 16; ++nt) {
        #pragma unroll
        for (int kk = 0; kk < 4; ++kk)
            acc[nt] = __builtin_amdgcn_mfma_f32_16x16x32_bf16(
                a[kk], bp[(nt * 4 + kk) * 64 + lane], acc[nt], 0, 0, 0);
    }

    #pragma unroll
    for (int r = 0; r < 4; ++r) {
        int node = base + (lane >> 4) * 4 + r;
        if (node < N_NODES) {
            unsigned* op = (unsigned*)&h1b[(size_t)node * HC + 2 * (lane & 15)];
            #pragma unroll
            for (int t = 0; t < 8; ++t)
                op[t * 16] = pack2(acc[2 * t][r], acc[2 * t + 1][r]);
        }
    }

    float asv[16], adv[16];
    #pragma unroll
    for (int nt = 0; nt < 16; ++nt) {
        int n = (nt >> 1) * 32 + 2 * (lane & 15) + (nt & 1);
        asv[nt] = a_src[n];
        adv[nt] = a_dst[n];
    }
    #pragma unroll
    for (int h = 0; h < HEADS; ++h) {
        #pragma unroll
        for (int r = 0; r < 4; ++r) {
            float s = acc[2 * h][r] * asv[2 * h] + acc[2 * h + 1][r] * asv[2 * h + 1];
            float d = acc[2 * h][r] * adv[2 * h] + acc[2 * h + 1][r] * adv[2 * h + 1];
            s += __shfl_xor(s, 1, 64); s += __shfl_xor(s, 2, 64);
            s += __shfl_xor(s, 4, 64); s += __shfl_xor(s, 8, 64);
            d += __shfl_xor(d, 1, 64); d += __shfl_xor(d, 2, 64);
            d += __shfl_xor(d, 4, 64); d += __shfl_xor(d, 8, 64);
            int node = base + (lane >> 4) * 4 + r;
            if ((lane & 15) == 0 && node < N_NODES) {
                al[node * HEADS + h] = s;
                ar[node * HEADS + h] = d;
            }
        }
    }
}

// ===== Layer 1 fused single-pass aggregation (R12 form, unchanged) ==========
__global__ __launch_bounds__(256) void aggr1_csr(
        const int* __restrict__ rowstart, const int* __restrict__ col,
        const float* __restrict__ al, const float* __restrict__ ar,
        const unsigned short* __restrict__ h1b, const float* __restrict__ b1,
        unsigned short* __restrict__ out1b) {
    const int lane = threadIdx.x & 63;
    const int d = blockIdx.x * 4 + (threadIdx.x >> 6);
    if (d >= N_NODES) return;
    const int beg = rowstart[d], end = rowstart[d + 1];

    const int eq = lane >> 3;                    // my exp edge slot 0..7
    const int eh = lane & 7;                     // my exp head
    const float ar_eh = ar[d * HEADS + eh];
    const int half = lane >> 5;                  // gather: 0 = even, 1 = odd edges
    const int L    = lane & 31;                  // channel block c = L*8..L*8+7
    const int hh   = L >> 2;                     // head of my channels

    float dsum = 0.f;
    float acc8[8] = {0.f,0.f,0.f,0.f,0.f,0.f,0.f,0.f};

    for (int i = beg; i < end; i += 8) {
        const int e = i + eq;
        const int sv_e = col[e < end ? e : end - 1];
        const float ex = (e < end) ? lrexp(al[sv_e * HEADS + eh] + ar_eh) : 0.f;
        dsum += ex;
        #pragma unroll
        for (int q = 0; q < 4; ++q) {
            const int src = (2 * q + half) * 8;
            const int   sq = __shfl(sv_e, src, 64);
            const float wq = __shfl(ex, src + hh, 64);
            const u16x8 v = *(const u16x8*)&h1b[(size_t)sq * HC + L * 8];
            #pragma unroll
            for (int j = 0; j < 8; ++j) acc8[j] += wq * bf2f(v[j]);
        }
    }
    dsum += __shfl_xor(dsum, 8, 64);
    dsum += __shfl_xor(dsum, 16, 64);
    dsum += __shfl_xor(dsum, 32, 64);
    const float inv = 1.f / (__shfl(dsum, hh, 64) + 1e-16f);
    #pragma unroll
    for (int j = 0; j < 8; ++j) acc8[j] *= inv;
    #pragma unroll
    for (int j = 0; j < 8; ++j) acc8[j] += __shfl_xor(acc8[j], 32, 64);

    if (half == 0) {
        const float4 b0 = *(const float4*)&b1[L * 8];
        const float4 b4 = *(const float4*)&b1[L * 8 + 4];
        float bb[8] = {b0.x, b0.y, b0.z, b0.w, b4.x, b4.y, b4.z, b4.w};
        u16x8 ov;
        #pragma unroll
        for (int j = 0; j < 8; ++j) {
            float v = acc8[j] + bb[j];
            v = v > 0.f ? v : expf(v) - 1.f;
            ov[j] = f2bf(v);
        }
        *(u16x8*)&out1b[(size_t)d * HC + L * 8] = ov;
    }
}

// ====== Layer 2 MFMA GEMM + fused logits: h2b(bf16), al2, ar2 ===============
__global__ __launch_bounds__(256) void gemm2_mfma(
        const ushort_t* __restrict__ hinb, const ushort_t* __restrict__ W2f,
        const float* __restrict__ a_src, const float* __restrict__ a_dst,
        ushort_t* __restrict__ h2b, float* __restrict__ al, float* __restrict__ ar) {
    const int lane = threadIdx.x & 63;
    const int wv   = threadIdx.x >> 6;
    const int base = blockIdx.x * 64 + wv * 16;
    if (base >= N_NODES) return;
    const int am = base + (lane & 15);
    const int rm = am < N_NODES ? am : N_NODES - 1;

    bf16x8 a[8];
    const bf16x8* ap = (const bf16x8*)&hinb[(size_t)rm * HC];
    #pragma unroll
    for (int kk = 0; kk < 8; ++kk)
        a[kk] = ap[kk * 4 + (lane >> 4)];

    f32x4 acc[4];
    #pragma unroll
    for (int nt = 0; nt < 4; ++nt) acc[nt] = (f32x4){0.f, 0.f, 0.f, 0.f};

    const bf16x8* bp = (const bf16x8*)W2f;
    #pragma unroll
    for (int nt = 0; nt < 4; ++nt) {
        #pragma unroll
        for (int kk = 0; kk < 8; ++kk)
            acc[nt] = __builtin_amdgcn_mfma_f32_16x16x32_bf16(
                a[kk], bp[(nt * 8 + kk) * 64 + lane], acc[nt], 0, 0, 0);
    }

    #pragma unroll
    for (int r = 0; r < 4; ++r) {
        int node = base + (lane >> 4) * 4 + r;
        if (node < N_NODES) {
            unsigned* op = (unsigned*)&h2b[(size_t)node * OUTC + 2 * (lane & 15)];
            #pragma unroll
            for (int t = 0; t < 2; ++t)
                op[t * 16] = pack2(acc[2 * t][r], acc[2 * t + 1][r]);
        }
    }

    float asv[4], adv[4];
    #pragma unroll
    for (int nt = 0; nt < 4; ++nt) {
        int n = (nt >> 1) * 32 + 2 * (lane & 15) + (nt & 1);
        asv[nt] = a_src[n];
        adv[nt] = a_dst[n];
    }
    #pragma unroll
    for (int r = 0; r < 4; ++r) {
        float s = 0.f, d = 0.f;
        #pragma unroll
        for (int nt = 0; nt < 4; ++nt) {
            s += acc[nt][r] * asv[nt];
            d += acc[nt][r] * adv[nt];
        }
        s += __shfl_xor(s, 1, 64); s += __shfl_xor(s, 2, 64);
        s += __shfl_xor(s, 4, 64); s += __shfl_xor(s, 8, 64);
        d += __shfl_xor(d, 1, 64); d += __shfl_xor(d, 2, 64);
        d += __shfl_xor(d, 4, 64); d += __shfl_xor(d, 8, 64);
        int node = base + (lane >> 4) * 4 + r;
        if ((lane & 15) == 0 && node < N_NODES) { al[node] = s; ar[node] = d; }
    }
}

// ===== Layer 2 fused single-pass aggregation (R12 form, unchanged) ==========
__global__ __launch_bounds__(256) void aggr2_csr(
        const int* __restrict__ rowstart, const int* __restrict__ col,
        const float* __restrict__ al, const float* __restrict__ ar,
        const unsigned short* __restrict__ h2b, const float* __restrict__ b2,
        float* __restrict__ out) {
    const int lane = threadIdx.x & 63;
    const int d = blockIdx.x * 4 + (threadIdx.x >> 6);
    if (d >= N_NODES) return;
    const int beg = rowstart[d], end = rowstart[d + 1];
    const float ard = ar[d];

    const int e8 = lane & 7;
    const int g  = lane >> 4;
    const int L  = lane & 15;

    float dsum = 0.f;
    float4 acc = {0.f, 0.f, 0.f, 0.f};

    for (int i = beg; i < end; i += 8) {
        const int e = i + e8;
        const int sv_e = col[e < end ? e : end - 1];
        const float ex = (e < end) ? lrexp(al[sv_e] + ard) : 0.f;
        dsum += ex;
        #pragma unroll
        for (int q = 0; q < 2; ++q) {
            const int slot = q * 4 + g;
            const int   sq = __shfl(sv_e, slot, 64);
            const float wq = __shfl(ex, slot, 64);
            const ushort4 v = *(const ushort4*)&h2b[(size_t)sq * OUTC + L * 4];
            acc.x += wq * bf2f(v.x); acc.y += wq * bf2f(v.y);
            acc.z += wq * bf2f(v.z); acc.w += wq * bf2f(v.w);
        }
    }
    dsum += __shfl_xor(dsum, 1, 64);
    dsum += __shfl_xor(dsum, 2, 64);
    dsum += __shfl_xor(dsum, 4, 64);
    const float inv = 1.f / (dsum + 1e-16f);
    acc.x *= inv; acc.y *= inv; acc.z *= inv; acc.w *= inv;
    #pragma unroll
    for (int o = 16; o < 64; o <<= 1) {
        acc.x += __shfl_xor(acc.x, o, 64);
        acc.y += __shfl_xor(acc.y, o, 64);
        acc.z += __shfl_xor(acc.z, o, 64);
        acc.w += __shfl_xor(acc.w, o, 64);
    }
    if (g == 0) {
        const float4 bb = *(const float4*)&b2[L * 4];
        float4 ov = { acc.x + bb.x, acc.y + bb.y, acc.z + bb.z, acc.w + bb.w };
        *(float4*)&out[(size_t)d * OUTC + L * 4] = ov;
    }
}

extern "C" void kernel_launch(void* const* d_in, const int* in_sizes, int n_in,
                              void* d_out, int out_size, void* d_ws, size_t ws_size,
                              hipStream_t stream) {
    const int*   ei     = (const int*)  d_in[1];
    const float* x      = (const float*)d_in[0];
    const float* W1     = (const float*)d_in[2];
    const float* a_src1 = (const float*)d_in[3];
    const float* a_dst1 = (const float*)d_in[4];
    const float* b1     = (const float*)d_in[5];
    const float* W2     = (const float*)d_in[6];
    const float* a_src2 = (const float*)d_in[7];
    const float* a_dst2 = (const float*)d_in[8];
    const float* b2     = (const float*)d_in[9];
    float* out = (float*)d_out;

    // ---- workspace layout ----
    char* p = (char*)d_ws;
    ushort_t* h1b   = (ushort_t*)p; p += (size_t)N_NODES * HC * 2;   // 25.6 MB
    ushort_t* out1b = (ushort_t*)p; p += (size_t)N_NODES * HC * 2;   // 25.6 MB
    ushort_t* h2b   = (ushort_t*)p; p += (size_t)N_NODES * OUTC * 2; // 6.4 MB
    ushort_t* W1f  = (ushort_t*)p; p += 32768 * 2;                   // 64 KB
    ushort_t* W2f  = (ushort_t*)p; p += 16384 * 2;                   // 32 KB
    float* al1  = (float*)p;  p += (size_t)N_NODES * HEADS * sizeof(float);
    float* ar1  = (float*)p;  p += (size_t)N_NODES * HEADS * sizeof(float);
    float* al2  = (float*)p;  p += (size_t)N_NODES * sizeof(float);
    float* ar2  = (float*)p;  p += (size_t)N_NODES * sizeof(float);
    int* deg      = (int*)p;  p += (size_t)N_NODES * sizeof(int);
    int* inc      = (int*)p;  p += (size_t)N_NODES * sizeof(int);
    int* bsum     = (int*)p;  p += (size_t)NSCANB * sizeof(int);
    int* rowstart = (int*)p;  p += (size_t)(N_NODES + 1) * sizeof(int);
    int* cursor   = (int*)p;  p += (size_t)N_NODES * sizeof(int);
    int* col      = (int*)p;  p += (size_t)E_TOT * sizeof(int);

    // ---- CSR build + weight repack: ONE cooperative kernel ----
    {
        void* args[] = {
            (void*)&ei, (void*)&W1, (void*)&W2, (void*)&W1f, (void*)&W2f,
            (void*)&deg, (void*)&inc, (void*)&bsum,
            (void*)&rowstart, (void*)&cursor, (void*)&col
        };
        hipLaunchCooperativeKernel((void*)csr_coop, dim3(COOP_BLOCKS), dim3(256),
                                   args, 0, stream);
    }

    // ---- layer 1 ----
    gemm1_mfma <<<(N_NODES + 63)/64, 256, 0, stream>>>(x, W1f, a_src1, a_dst1, h1b, al1, ar1);
    aggr1_csr  <<<(N_NODES + 3)/4, 256, 0, stream>>>(rowstart, col, al1, ar1, h1b, b1, out1b);

    // ---- layer 2 ----
    gemm2_mfma <<<(N_NODES + 63)/64, 256, 0, stream>>>(out1b, W2f, a_src2, a_dst2, h2b, al2, ar2);
    aggr2_csr  <<<(N_NODES + 3)/4, 256, 0, stream>>>(rowstart, col, al2, ar2, h2b, b2, out);
}

// Round 14
// 256.081 us; speedup vs baseline: 2.4886x; 2.4886x over previous
//
#include <hip/hip_runtime.h>
#include <cstdint>

#define N_NODES 50000
#define N_EDGES 800000
#define E_TOT   (N_EDGES + N_NODES)   // 850000 with self-loops
#define IN_CH   128
#define HEADS   8
#define CCH     32
#define HC      256                    // HEADS*CCH
#define OUTC    64
#define NSCANB  196                    // 196*256 = 50176 >= N_NODES

typedef unsigned short ushort_t;
typedef __attribute__((ext_vector_type(8))) short bf16x8;
typedef __attribute__((ext_vector_type(8))) unsigned short u16x8;
typedef __attribute__((ext_vector_type(4))) float f32x4;

// bf16 helpers (RNE rounding on pack)
static __device__ __forceinline__ unsigned short f2bf(float f) {
    unsigned u = __float_as_uint(f);
    u = u + 0x7fffu + ((u >> 16) & 1u);
    return (unsigned short)(u >> 16);
}
static __device__ __forceinline__ float bf2f(unsigned short h) {
    return __uint_as_float((unsigned)h << 16);
}
static __device__ __forceinline__ unsigned pack2(float lo, float hi) {
    return (unsigned)f2bf(lo) | ((unsigned)f2bf(hi) << 16);
}
static __device__ __forceinline__ float lrexp(float v) {
    v = v > 0.f ? v : 0.2f * v;        // LeakyReLU(0.2)
    return expf(v);
}
static __device__ __forceinline__ bf16x8 cvt8(float4 lo, float4 hi) {
    bf16x8 r;
    r[0] = (short)f2bf(lo.x); r[1] = (short)f2bf(lo.y);
    r[2] = (short)f2bf(lo.z); r[3] = (short)f2bf(lo.w);
    r[4] = (short)f2bf(hi.x); r[5] = (short)f2bf(hi.y);
    r[6] = (short)f2bf(hi.z); r[7] = (short)f2bf(hi.w);
    return r;
}

// ===== prep: weight repack (first blocks) + degree histogram (all blocks) ====
// MFMA tile nt covers output col(nt,c) = (nt>>1)*32 + 2*c + (nt&1), c=lane&15.
__global__ __launch_bounds__(256) void prep_kernel(
        const int* __restrict__ ei, int* __restrict__ deg,
        const float* __restrict__ W1, const float* __restrict__ W2,
        ushort_t* __restrict__ W1f, ushort_t* __restrict__ W2f) {
    int t = blockIdx.x * 256 + threadIdx.x;
    if (t < 32768) {
        int j = t & 7, lane = (t >> 3) & 63, f = t >> 9;
        int nt = f >> 2, kk = f & 3;
        int k = kk * 32 + (lane >> 4) * 8 + j;
        int n = (nt >> 1) * 32 + 2 * (lane & 15) + (nt & 1);
        W1f[t] = f2bf(W1[k * HC + n]);
    } else if (t < 32768 + 16384) {
        int u = t - 32768;
        int j = u & 7, lane = (u >> 3) & 63, f = u >> 9;
        int nt = f >> 3, kk = f & 7;
        int k = kk * 32 + (lane >> 4) * 8 + j;
        int n = (nt >> 1) * 32 + 2 * (lane & 15) + (nt & 1);
        W2f[u] = f2bf(W2[k * OUTC + n]);
    }
    if (t < E_TOT) {
        int dv = (t < N_EDGES) ? ei[N_EDGES + t] : (t - N_EDGES);
        atomicAdd(&deg[dv], 1);
    }
}

// ===== scan1: 196 x 256, wave-shuffle inclusive scan (1 barrier) ============
__global__ __launch_bounds__(256) void scan1_kernel(
        const int* __restrict__ deg, int* __restrict__ inc, int* __restrict__ bsum) {
    const int i = blockIdx.x * 256 + threadIdx.x;
    const int lane = threadIdx.x & 63;
    const int w    = threadIdx.x >> 6;
    int v = (i < N_NODES) ? deg[i] : 0;
    #pragma unroll
    for (int o = 1; o < 64; o <<= 1) {
        int t = __shfl_up(v, o, 64);
        if (lane >= o) v += t;
    }
    __shared__ int wsum[4];
    if (lane == 63) wsum[w] = v;
    __syncthreads();
    int add = 0;
    #pragma unroll
    for (int k = 0; k < 4; ++k) add += (k < w) ? wsum[k] : 0;
    v += add;
    if (i < N_NODES) inc[i] = v;
    if (threadIdx.x == 255) bsum[blockIdx.x] = v;
}

// finalize with scan2 folded in: every block redundantly prefix-sums bsum[196]
__global__ __launch_bounds__(256) void finalize_kernel(
        const int* __restrict__ inc, const int* __restrict__ bsum,
        int* __restrict__ rowstart, int* __restrict__ cursor) {
    __shared__ int pref[NSCANB];
    if (threadIdx.x == 0) {
        int acc = 0;
        for (int k = 0; k < NSCANB; ++k) { pref[k] = acc; acc += bsum[k]; }
    }
    __syncthreads();
    int i = blockIdx.x * 256 + threadIdx.x;
    if (i >= N_NODES) return;
    int v = inc[i] + pref[i >> 8];
    rowstart[i + 1] = v;
    if (i + 1 < N_NODES) cursor[i + 1] = v;
    if (i == 0) { rowstart[0] = 0; cursor[0] = 0; }
}

__global__ __launch_bounds__(256) void scatter_kernel(
        const int* __restrict__ ei, int* __restrict__ cursor, int* __restrict__ col) {
    int e = blockIdx.x * 256 + threadIdx.x;
    if (e >= E_TOT) return;
    int sv, dv;
    if (e < N_EDGES) { sv = ei[e]; dv = ei[N_EDGES + e]; }
    else             { sv = dv = e - N_EDGES; }
    int pos = atomicAdd(&cursor[dv], 1);
    col[pos] = sv;
}

// ====== Layer 1 MFMA GEMM + fused logits: h1b(bf16), al1, ar1 ===============
__global__ __launch_bounds__(256) void gemm1_mfma(
        const float* __restrict__ x, const ushort_t* __restrict__ W1f,
        const float* __restrict__ a_src, const float* __restrict__ a_dst,
        ushort_t* __restrict__ h1b, float* __restrict__ al, float* __restrict__ ar) {
    const int lane = threadIdx.x & 63;
    const int wv   = threadIdx.x >> 6;
    const int base = blockIdx.x * 64 + wv * 16;
    if (base >= N_NODES) return;
    const int am = base + (lane & 15);
    const int rm = am < N_NODES ? am : N_NODES - 1;

    bf16x8 a[4];
    const float* xr = &x[(size_t)rm * IN_CH + (lane >> 4) * 8];
    #pragma unroll
    for (int kk = 0; kk < 4; ++kk) {
        float4 lo = *(const float4*)&xr[kk * 32];
        float4 hi = *(const float4*)&xr[kk * 32 + 4];
        a[kk] = cvt8(lo, hi);
    }

    f32x4 acc[16];
    #pragma unroll
    for (int nt = 0; nt < 16; ++nt) acc[nt] = (f32x4){0.f, 0.f, 0.f, 0.f};

    const bf16x8* bp = (const bf16x8*)W1f;
    #pragma unroll
    for (int nt = 0; nt < 16; ++nt) {
        #pragma unroll
        for (int kk = 0; kk < 4; ++kk)
            acc[nt] = __builtin_amdgcn_mfma_f32_16x16x32_bf16(
                a[kk], bp[(nt * 4 + kk) * 64 + lane], acc[nt], 0, 0, 0);
    }

    #pragma unroll
    for (int r = 0; r < 4; ++r) {
        int node = base + (lane >> 4) * 4 + r;
        if (node < N_NODES) {
            unsigned* op = (unsigned*)&h1b[(size_t)node * HC + 2 * (lane & 15)];
            #pragma unroll
            for (int t = 0; t < 8; ++t)
                op[t * 16] = pack2(acc[2 * t][r], acc[2 * t + 1][r]);
        }
    }

    float asv[16], adv[16];
    #pragma unroll
    for (int nt = 0; nt < 16; ++nt) {
        int n = (nt >> 1) * 32 + 2 * (lane & 15) + (nt & 1);
        asv[nt] = a_src[n];
        adv[nt] = a_dst[n];
    }
    #pragma unroll
    for (int h = 0; h < HEADS; ++h) {
        #pragma unroll
        for (int r = 0; r < 4; ++r) {
            float s = acc[2 * h][r] * asv[2 * h] + acc[2 * h + 1][r] * asv[2 * h + 1];
            float d = acc[2 * h][r] * adv[2 * h] + acc[2 * h + 1][r] * adv[2 * h + 1];
            s += __shfl_xor(s, 1, 64); s += __shfl_xor(s, 2, 64);
            s += __shfl_xor(s, 4, 64); s += __shfl_xor(s, 8, 64);
            d += __shfl_xor(d, 1, 64); d += __shfl_xor(d, 2, 64);
            d += __shfl_xor(d, 4, 64); d += __shfl_xor(d, 8, 64);
            int node = base + (lane >> 4) * 4 + r;
            if ((lane & 15) == 0 && node < N_NODES) {
                al[node * HEADS + h] = s;
                ar[node * HEADS + h] = d;
            }
        }
    }
}

// ===== Layer 1 fused single-pass aggregation (R12 form) =====================
__global__ __launch_bounds__(256) void aggr1_csr(
        const int* __restrict__ rowstart, const int* __restrict__ col,
        const float* __restrict__ al, const float* __restrict__ ar,
        const unsigned short* __restrict__ h1b, const float* __restrict__ b1,
        unsigned short* __restrict__ out1b) {
    const int lane = threadIdx.x & 63;
    const int d = blockIdx.x * 4 + (threadIdx.x >> 6);
    if (d >= N_NODES) return;
    const int beg = rowstart[d], end = rowstart[d + 1];

    const int eq = lane >> 3;                    // my exp edge slot 0..7
    const int eh = lane & 7;                     // my exp head
    const float ar_eh = ar[d * HEADS + eh];
    const int half = lane >> 5;                  // gather: 0 = even, 1 = odd edges
    const int L    = lane & 31;                  // channel block c = L*8..L*8+7
    const int hh   = L >> 2;                     // head of my channels

    float dsum = 0.f;
    float acc8[8] = {0.f,0.f,0.f,0.f,0.f,0.f,0.f,0.f};

    for (int i = beg; i < end; i += 8) {
        const int e = i + eq;
        const int sv_e = col[e < end ? e : end - 1];
        const float ex = (e < end) ? lrexp(al[sv_e * HEADS + eh] + ar_eh) : 0.f;
        dsum += ex;
        #pragma unroll
        for (int q = 0; q < 4; ++q) {
            const int src = (2 * q + half) * 8;
            const int   sq = __shfl(sv_e, src, 64);
            const float wq = __shfl(ex, src + hh, 64);
            const u16x8 v = *(const u16x8*)&h1b[(size_t)sq * HC + L * 8];
            #pragma unroll
            for (int j = 0; j < 8; ++j) acc8[j] += wq * bf2f(v[j]);
        }
    }
    dsum += __shfl_xor(dsum, 8, 64);
    dsum += __shfl_xor(dsum, 16, 64);
    dsum += __shfl_xor(dsum, 32, 64);
    const float inv = 1.f / (__shfl(dsum, hh, 64) + 1e-16f);
    #pragma unroll
    for (int j = 0; j < 8; ++j) acc8[j] *= inv;
    #pragma unroll
    for (int j = 0; j < 8; ++j) acc8[j] += __shfl_xor(acc8[j], 32, 64);

    if (half == 0) {
        const float4 b0 = *(const float4*)&b1[L * 8];
        const float4 b4 = *(const float4*)&b1[L * 8 + 4];
        float bb[8] = {b0.x, b0.y, b0.z, b0.w, b4.x, b4.y, b4.z, b4.w};
        u16x8 ov;
        #pragma unroll
        for (int j = 0; j < 8; ++j) {
            float v = acc8[j] + bb[j];
            v = v > 0.f ? v : expf(v) - 1.f;
            ov[j] = f2bf(v);
        }
        *(u16x8*)&out1b[(size_t)d * HC + L * 8] = ov;
    }
}

// ====== Layer 2 MFMA GEMM + fused logits: h2b(bf16), al2, ar2 ===============
__global__ __launch_bounds__(256) void gemm2_mfma(
        const ushort_t* __restrict__ hinb, const ushort_t* __restrict__ W2f,
        const float* __restrict__ a_src, const float* __restrict__ a_dst,
        ushort_t* __restrict__ h2b, float* __restrict__ al, float* __restrict__ ar) {
    const int lane = threadIdx.x & 63;
    const int wv   = threadIdx.x >> 6;
    const int base = blockIdx.x * 64 + wv * 16;
    if (base >= N_NODES) return;
    const int am = base + (lane & 15);
    const int rm = am < N_NODES ? am : N_NODES - 1;

    bf16x8 a[8];
    const bf16x8* ap = (const bf16x8*)&hinb[(size_t)rm * HC];
    #pragma unroll
    for (int kk = 0; kk < 8; ++kk)
        a[kk] = ap[kk * 4 + (lane >> 4)];

    f32x4 acc[4];
    #pragma unroll
    for (int nt = 0; nt < 4; ++nt) acc[nt] = (f32x4){0.f, 0.f, 0.f, 0.f};

    const bf16x8* bp = (const bf16x8*)W2f;
    #pragma unroll
    for (int nt = 0; nt < 4; ++nt) {
        #pragma unroll
        for (int kk = 0; kk < 8; ++kk)
            acc[nt] = __builtin_amdgcn_mfma_f32_16x16x32_bf16(
                a[kk], bp[(nt * 8 + kk) * 64 + lane], acc[nt], 0, 0, 0);
    }

    #pragma unroll
    for (int r = 0; r < 4; ++r) {
        int node = base + (lane >> 4) * 4 + r;
        if (node < N_NODES) {
            unsigned* op = (unsigned*)&h2b[(size_t)node * OUTC + 2 * (lane & 15)];
            #pragma unroll
            for (int t = 0; t < 2; ++t)
                op[t * 16] = pack2(acc[2 * t][r], acc[2 * t + 1][r]);
        }
    }

    float asv[4], adv[4];
    #pragma unroll
    for (int nt = 0; nt < 4; ++nt) {
        int n = (nt >> 1) * 32 + 2 * (lane & 15) + (nt & 1);
        asv[nt] = a_src[n];
        adv[nt] = a_dst[n];
    }
    #pragma unroll
    for (int r = 0; r < 4; ++r) {
        float s = 0.f, d = 0.f;
        #pragma unroll
        for (int nt = 0; nt < 4; ++nt) {
            s += acc[nt][r] * asv[nt];
            d += acc[nt][r] * adv[nt];
        }
        s += __shfl_xor(s, 1, 64); s += __shfl_xor(s, 2, 64);
        s += __shfl_xor(s, 4, 64); s += __shfl_xor(s, 8, 64);
        d += __shfl_xor(d, 1, 64); d += __shfl_xor(d, 2, 64);
        d += __shfl_xor(d, 4, 64); d += __shfl_xor(d, 8, 64);
        int node = base + (lane >> 4) * 4 + r;
        if ((lane & 15) == 0 && node < N_NODES) { al[node] = s; ar[node] = d; }
    }
}

// ===== Layer 2 fused single-pass aggregation (R12 form) =====================
__global__ __launch_bounds__(256) void aggr2_csr(
        const int* __restrict__ rowstart, const int* __restrict__ col,
        const float* __restrict__ al, const float* __restrict__ ar,
        const unsigned short* __restrict__ h2b, const float* __restrict__ b2,
        float* __restrict__ out) {
    const int lane = threadIdx.x & 63;
    const int d = blockIdx.x * 4 + (threadIdx.x >> 6);
    if (d >= N_NODES) return;
    const int beg = rowstart[d], end = rowstart[d + 1];
    const float ard = ar[d];

    const int e8 = lane & 7;
    const int g  = lane >> 4;
    const int L  = lane & 15;

    float dsum = 0.f;
    float4 acc = {0.f, 0.f, 0.f, 0.f};

    for (int i = beg; i < end; i += 8) {
        const int e = i + e8;
        const int sv_e = col[e < end ? e : end - 1];
        const float ex = (e < end) ? lrexp(al[sv_e] + ard) : 0.f;
        dsum += ex;
        #pragma unroll
        for (int q = 0; q < 2; ++q) {
            const int slot = q * 4 + g;
            const int   sq = __shfl(sv_e, slot, 64);
            const float wq = __shfl(ex, slot, 64);
            const ushort4 v = *(const ushort4*)&h2b[(size_t)sq * OUTC + L * 4];
            acc.x += wq * bf2f(v.x); acc.y += wq * bf2f(v.y);
            acc.z += wq * bf2f(v.z); acc.w += wq * bf2f(v.w);
        }
    }
    dsum += __shfl_xor(dsum, 1, 64);
    dsum += __shfl_xor(dsum, 2, 64);
    dsum += __shfl_xor(dsum, 4, 64);
    const float inv = 1.f / (dsum + 1e-16f);
    acc.x *= inv; acc.y *= inv; acc.z *= inv; acc.w *= inv;
    #pragma unroll
    for (int o = 16; o < 64; o <<= 1) {
        acc.x += __shfl_xor(acc.x, o, 64);
        acc.y += __shfl_xor(acc.y, o, 64);
        acc.z += __shfl_xor(acc.z, o, 64);
        acc.w += __shfl_xor(acc.w, o, 64);
    }
    if (g == 0) {
        const float4 bb = *(const float4*)&b2[L * 4];
        float4 ov = { acc.x + bb.x, acc.y + bb.y, acc.z + bb.z, acc.w + bb.w };
        *(float4*)&out[(size_t)d * OUTC + L * 4] = ov;
    }
}

extern "C" void kernel_launch(void* const* d_in, const int* in_sizes, int n_in,
                              void* d_out, int out_size, void* d_ws, size_t ws_size,
                              hipStream_t stream) {
    const float* x      = (const float*)d_in[0];
    const int*   ei     = (const int*)  d_in[1];
    const float* W1     = (const float*)d_in[2];
    const float* a_src1 = (const float*)d_in[3];
    const float* a_dst1 = (const float*)d_in[4];
    const float* b1     = (const float*)d_in[5];
    const float* W2     = (const float*)d_in[6];
    const float* a_src2 = (const float*)d_in[7];
    const float* a_dst2 = (const float*)d_in[8];
    const float* b2     = (const float*)d_in[9];
    float* out = (float*)d_out;

    // ---- workspace layout ----
    char* p = (char*)d_ws;
    ushort_t* h1b   = (ushort_t*)p; p += (size_t)N_NODES * HC * 2;   // 25.6 MB
    ushort_t* out1b = (ushort_t*)p; p += (size_t)N_NODES * HC * 2;   // 25.6 MB
    ushort_t* h2b   = (ushort_t*)p; p += (size_t)N_NODES * OUTC * 2; // 6.4 MB
    ushort_t* W1f  = (ushort_t*)p; p += 32768 * 2;                   // 64 KB
    ushort_t* W2f  = (ushort_t*)p; p += 16384 * 2;                   // 32 KB
    float* al1  = (float*)p;  p += (size_t)N_NODES * HEADS * sizeof(float);
    float* ar1  = (float*)p;  p += (size_t)N_NODES * HEADS * sizeof(float);
    float* al2  = (float*)p;  p += (size_t)N_NODES * sizeof(float);
    float* ar2  = (float*)p;  p += (size_t)N_NODES * sizeof(float);
    int* deg      = (int*)p;  p += (size_t)N_NODES * sizeof(int);
    int* inc      = (int*)p;  p += (size_t)N_NODES * sizeof(int);
    int* bsum     = (int*)p;  p += (size_t)NSCANB * sizeof(int);
    int* rowstart = (int*)p;  p += (size_t)(N_NODES + 1) * sizeof(int);
    int* cursor   = (int*)p;  p += (size_t)N_NODES * sizeof(int);
    int* col      = (int*)p;  p += (size_t)E_TOT * sizeof(int);

    // ---- CSR build + weight repack ----
    hipMemsetAsync(deg, 0, (size_t)N_NODES * sizeof(int), stream);
    prep_kernel    <<<(E_TOT + 255)/256, 256, 0, stream>>>(ei, deg, W1, W2, W1f, W2f);
    scan1_kernel   <<<NSCANB, 256, 0, stream>>>(deg, inc, bsum);
    finalize_kernel<<<(N_NODES + 255)/256, 256, 0, stream>>>(inc, bsum, rowstart, cursor);
    scatter_kernel <<<(E_TOT + 255)/256, 256, 0, stream>>>(ei, cursor, col);

    // ---- layer 1 ----
    gemm1_mfma <<<(N_NODES + 63)/64, 256, 0, stream>>>(x, W1f, a_src1, a_dst1, h1b, al1, ar1);
    aggr1_csr  <<<(N_NODES + 3)/4, 256, 0, stream>>>(rowstart, col, al1, ar1, h1b, b1, out1b);

    // ---- layer 2 ----
    gemm2_mfma <<<(N_NODES + 63)/64, 256, 0, stream>>>(out1b, W2f, a_src2, a_dst2, h2b, al2, ar2);
    aggr2_csr  <<<(N_NODES + 3)/4, 256, 0, stream>>>(rowstart, col, al2, ar2, h2b, b2, out);
}

// Round 15
// 251.470 us; speedup vs baseline: 2.5342x; 1.0183x over previous
//
#include <hip/hip_runtime.h>
#include <cstdint>

#define N_NODES 50000
#define N_EDGES 800000
#define E_TOT   (N_EDGES + N_NODES)   // 850000 with self-loops
#define IN_CH   128
#define HEADS   8
#define CCH     32
#define HC      256                    // HEADS*CCH
#define OUTC    64
#define NSCANB  196                    // 196*256 = 50176 >= N_NODES

typedef unsigned short ushort_t;
typedef __attribute__((ext_vector_type(8))) short bf16x8;
typedef __attribute__((ext_vector_type(8))) unsigned short u16x8;
typedef __attribute__((ext_vector_type(4))) float f32x4;

// bf16 helpers (RNE rounding on pack)
static __device__ __forceinline__ unsigned short f2bf(float f) {
    unsigned u = __float_as_uint(f);
    u = u + 0x7fffu + ((u >> 16) & 1u);
    return (unsigned short)(u >> 16);
}
static __device__ __forceinline__ float bf2f(unsigned short h) {
    return __uint_as_float((unsigned)h << 16);
}
static __device__ __forceinline__ unsigned pack2(float lo, float hi) {
    return (unsigned)f2bf(lo) | ((unsigned)f2bf(hi) << 16);
}
static __device__ __forceinline__ float lrexp(float v) {
    v = v > 0.f ? v : 0.2f * v;        // LeakyReLU(0.2)
    return expf(v);
}
static __device__ __forceinline__ bf16x8 cvt8(float4 lo, float4 hi) {
    bf16x8 r;
    r[0] = (short)f2bf(lo.x); r[1] = (short)f2bf(lo.y);
    r[2] = (short)f2bf(lo.z); r[3] = (short)f2bf(lo.w);
    r[4] = (short)f2bf(hi.x); r[5] = (short)f2bf(hi.y);
    r[6] = (short)f2bf(hi.z); r[7] = (short)f2bf(hi.w);
    return r;
}

// ===== prep: weight repack (first blocks) + degree histogram (all blocks) ====
// MFMA tile nt covers output col(nt,c) = (nt>>1)*32 + 2*c + (nt&1), c=lane&15.
__global__ __launch_bounds__(256) void prep_kernel(
        const int* __restrict__ ei, int* __restrict__ deg,
        const float* __restrict__ W1, const float* __restrict__ W2,
        ushort_t* __restrict__ W1f, ushort_t* __restrict__ W2f) {
    int t = blockIdx.x * 256 + threadIdx.x;
    if (t < 32768) {
        int j = t & 7, lane = (t >> 3) & 63, f = t >> 9;
        int nt = f >> 2, kk = f & 3;
        int k = kk * 32 + (lane >> 4) * 8 + j;
        int n = (nt >> 1) * 32 + 2 * (lane & 15) + (nt & 1);
        W1f[t] = f2bf(W1[k * HC + n]);
    } else if (t < 32768 + 16384) {
        int u = t - 32768;
        int j = u & 7, lane = (u >> 3) & 63, f = u >> 9;
        int nt = f >> 3, kk = f & 7;
        int k = kk * 32 + (lane >> 4) * 8 + j;
        int n = (nt >> 1) * 32 + 2 * (lane & 15) + (nt & 1);
        W2f[u] = f2bf(W2[k * OUTC + n]);
    }
    if (t < E_TOT) {
        int dv = (t < N_EDGES) ? ei[N_EDGES + t] : (t - N_EDGES);
        atomicAdd(&deg[dv], 1);
    }
}

// ===== scan1: 196 x 256, wave-shuffle inclusive scan (1 barrier) ============
__global__ __launch_bounds__(256) void scan1_kernel(
        const int* __restrict__ deg, int* __restrict__ inc, int* __restrict__ bsum) {
    const int i = blockIdx.x * 256 + threadIdx.x;
    const int lane = threadIdx.x & 63;
    const int w    = threadIdx.x >> 6;
    int v = (i < N_NODES) ? deg[i] : 0;
    #pragma unroll
    for (int o = 1; o < 64; o <<= 1) {
        int t = __shfl_up(v, o, 64);
        if (lane >= o) v += t;
    }
    __shared__ int wsum[4];
    if (lane == 63) wsum[w] = v;
    __syncthreads();
    int add = 0;
    #pragma unroll
    for (int k = 0; k < 4; ++k) add += (k < w) ? wsum[k] : 0;
    v += add;
    if (i < N_NODES) inc[i] = v;
    if (threadIdx.x == 255) bsum[blockIdx.x] = v;
}

// finalize: parallel wave-scan of bsum[196] (replaces serial thread-0 loop)
__global__ __launch_bounds__(256) void finalize_kernel(
        const int* __restrict__ inc, const int* __restrict__ bsum,
        int* __restrict__ rowstart, int* __restrict__ cursor) {
    __shared__ int pref[256];
    __shared__ int wsum[4];
    {
        const int t    = threadIdx.x;
        const int lane = t & 63;
        const int w    = t >> 6;
        int v = (t < NSCANB) ? bsum[t] : 0;
        int excl_in = v;                     // save own value for exclusive
        #pragma unroll
        for (int o = 1; o < 64; o <<= 1) {
            int s = __shfl_up(v, o, 64);
            if (lane >= o) v += s;
        }
        if (lane == 63) wsum[w] = v;
        __syncthreads();
        int add = 0;
        #pragma unroll
        for (int k = 0; k < 4; ++k) add += (k < w) ? wsum[k] : 0;
        pref[t] = v + add - excl_in;         // exclusive prefix of bsum
        __syncthreads();
    }
    int i = blockIdx.x * 256 + threadIdx.x;
    if (i >= N_NODES) return;
    int v = inc[i] + pref[i >> 8];
    rowstart[i + 1] = v;
    if (i + 1 < N_NODES) cursor[i + 1] = v;
    if (i == 0) { rowstart[0] = 0; cursor[0] = 0; }
}

__global__ __launch_bounds__(256) void scatter_kernel(
        const int* __restrict__ ei, int* __restrict__ cursor, int* __restrict__ col) {
    int e = blockIdx.x * 256 + threadIdx.x;
    if (e >= E_TOT) return;
    int sv, dv;
    if (e < N_EDGES) { sv = ei[e]; dv = ei[N_EDGES + e]; }
    else             { sv = dv = e - N_EDGES; }
    int pos = atomicAdd(&cursor[dv], 1);
    col[pos] = sv;
}

// ====== Layer 1 MFMA GEMM + fused logits: h1b(bf16), al1, ar1 ===============
__global__ __launch_bounds__(256) void gemm1_mfma(
        const float* __restrict__ x, const ushort_t* __restrict__ W1f,
        const float* __restrict__ a_src, const float* __restrict__ a_dst,
        ushort_t* __restrict__ h1b, float* __restrict__ al, float* __restrict__ ar) {
    const int lane = threadIdx.x & 63;
    const int wv   = threadIdx.x >> 6;
    const int base = blockIdx.x * 64 + wv * 16;
    if (base >= N_NODES) return;
    const int am = base + (lane & 15);
    const int rm = am < N_NODES ? am : N_NODES - 1;

    bf16x8 a[4];
    const float* xr = &x[(size_t)rm * IN_CH + (lane >> 4) * 8];
    #pragma unroll
    for (int kk = 0; kk < 4; ++kk) {
        float4 lo = *(const float4*)&xr[kk * 32];
        float4 hi = *(const float4*)&xr[kk * 32 + 4];
        a[kk] = cvt8(lo, hi);
    }

    f32x4 acc[16];
    #pragma unroll
    for (int nt = 0; nt < 16; ++nt) acc[nt] = (f32x4){0.f, 0.f, 0.f, 0.f};

    const bf16x8* bp = (const bf16x8*)W1f;
    #pragma unroll
    for (int nt = 0; nt < 16; ++nt) {
        #pragma unroll
        for (int kk = 0; kk < 4; ++kk)
            acc[nt] = __builtin_amdgcn_mfma_f32_16x16x32_bf16(
                a[kk], bp[(nt * 4 + kk) * 64 + lane], acc[nt], 0, 0, 0);
    }

    #pragma unroll
    for (int r = 0; r < 4; ++r) {
        int node = base + (lane >> 4) * 4 + r;
        if (node < N_NODES) {
            unsigned* op = (unsigned*)&h1b[(size_t)node * HC + 2 * (lane & 15)];
            #pragma unroll
            for (int t = 0; t < 8; ++t)
                op[t * 16] = pack2(acc[2 * t][r], acc[2 * t + 1][r]);
        }
    }

    float asv[16], adv[16];
    #pragma unroll
    for (int nt = 0; nt < 16; ++nt) {
        int n = (nt >> 1) * 32 + 2 * (lane & 15) + (nt & 1);
        asv[nt] = a_src[n];
        adv[nt] = a_dst[n];
    }
    #pragma unroll
    for (int h = 0; h < HEADS; ++h) {
        #pragma unroll
        for (int r = 0; r < 4; ++r) {
            float s = acc[2 * h][r] * asv[2 * h] + acc[2 * h + 1][r] * asv[2 * h + 1];
            float d = acc[2 * h][r] * adv[2 * h] + acc[2 * h + 1][r] * adv[2 * h + 1];
            s += __shfl_xor(s, 1, 64); s += __shfl_xor(s, 2, 64);
            s += __shfl_xor(s, 4, 64); s += __shfl_xor(s, 8, 64);
            d += __shfl_xor(d, 1, 64); d += __shfl_xor(d, 2, 64);
            d += __shfl_xor(d, 4, 64); d += __shfl_xor(d, 8, 64);
            int node = base + (lane >> 4) * 4 + r;
            if ((lane & 15) == 0 && node < N_NODES) {
                al[node * HEADS + h] = s;
                ar[node * HEADS + h] = d;
            }
        }
    }
}

// ===== Layer 1 fused single-pass aggregation ================================
__global__ __launch_bounds__(256) void aggr1_csr(
        const int* __restrict__ rowstart, const int* __restrict__ col,
        const float* __restrict__ al, const float* __restrict__ ar,
        const unsigned short* __restrict__ h1b, const float* __restrict__ b1,
        unsigned short* __restrict__ out1b) {
    const int lane = threadIdx.x & 63;
    const int d = blockIdx.x * 4 + (threadIdx.x >> 6);
    if (d >= N_NODES) return;
    const int beg = rowstart[d], end = rowstart[d + 1];

    const int eq = lane >> 3;                    // my exp edge slot 0..7
    const int eh = lane & 7;                     // my exp head
    const float ar_eh = ar[d * HEADS + eh];
    const int half = lane >> 5;                  // gather: 0 = even, 1 = odd edges
    const int L    = lane & 31;                  // channel block c = L*8..L*8+7
    const int hh   = L >> 2;                     // head of my channels

    float dsum = 0.f;
    float acc8[8] = {0.f,0.f,0.f,0.f,0.f,0.f,0.f,0.f};

    for (int i = beg; i < end; i += 8) {
        const int e = i + eq;
        const int sv_e = col[e < end ? e : end - 1];
        const float ex = (e < end) ? lrexp(al[sv_e * HEADS + eh] + ar_eh) : 0.f;
        dsum += ex;
        #pragma unroll
        for (int q = 0; q < 4; ++q) {
            const int src = (2 * q + half) * 8;
            const int   sq = __shfl(sv_e, src, 64);
            const float wq = __shfl(ex, src + hh, 64);
            const u16x8 v = *(const u16x8*)&h1b[(size_t)sq * HC + L * 8];
            #pragma unroll
            for (int j = 0; j < 8; ++j) acc8[j] += wq * bf2f(v[j]);
        }
    }
    dsum += __shfl_xor(dsum, 8, 64);
    dsum += __shfl_xor(dsum, 16, 64);
    dsum += __shfl_xor(dsum, 32, 64);
    const float inv = 1.f / (__shfl(dsum, hh, 64) + 1e-16f);
    #pragma unroll
    for (int j = 0; j < 8; ++j) acc8[j] *= inv;
    #pragma unroll
    for (int j = 0; j < 8; ++j) acc8[j] += __shfl_xor(acc8[j], 32, 64);

    if (half == 0) {
        const float4 b0 = *(const float4*)&b1[L * 8];
        const float4 b4 = *(const float4*)&b1[L * 8 + 4];
        float bb[8] = {b0.x, b0.y, b0.z, b0.w, b4.x, b4.y, b4.z, b4.w};
        u16x8 ov;
        #pragma unroll
        for (int j = 0; j < 8; ++j) {
            float v = acc8[j] + bb[j];
            v = v > 0.f ? v : expf(v) - 1.f;
            ov[j] = f2bf(v);
        }
        *(u16x8*)&out1b[(size_t)d * HC + L * 8] = ov;
    }
}

// ====== Layer 2 MFMA GEMM + fused logits: h2b(bf16), al2, ar2 ===============
__global__ __launch_bounds__(256) void gemm2_mfma(
        const ushort_t* __restrict__ hinb, const ushort_t* __restrict__ W2f,
        const float* __restrict__ a_src, const float* __restrict__ a_dst,
        ushort_t* __restrict__ h2b, float* __restrict__ al, float* __restrict__ ar) {
    const int lane = threadIdx.x & 63;
    const int wv   = threadIdx.x >> 6;
    const int base = blockIdx.x * 64 + wv * 16;
    if (base >= N_NODES) return;
    const int am = base + (lane & 15);
    const int rm = am < N_NODES ? am : N_NODES - 1;

    bf16x8 a[8];
    const bf16x8* ap = (const bf16x8*)&hinb[(size_t)rm * HC];
    #pragma unroll
    for (int kk = 0; kk < 8; ++kk)
        a[kk] = ap[kk * 4 + (lane >> 4)];

    f32x4 acc[4];
    #pragma unroll
    for (int nt = 0; nt < 4; ++nt) acc[nt] = (f32x4){0.f, 0.f, 0.f, 0.f};

    const bf16x8* bp = (const bf16x8*)W2f;
    #pragma unroll
    for (int nt = 0; nt < 4; ++nt) {
        #pragma unroll
        for (int kk = 0; kk < 8; ++kk)
            acc[nt] = __builtin_amdgcn_mfma_f32_16x16x32_bf16(
                a[kk], bp[(nt * 8 + kk) * 64 + lane], acc[nt], 0, 0, 0);
    }

    #pragma unroll
    for (int r = 0; r < 4; ++r) {
        int node = base + (lane >> 4) * 4 + r;
        if (node < N_NODES) {
            unsigned* op = (unsigned*)&h2b[(size_t)node * OUTC + 2 * (lane & 15)];
            #pragma unroll
            for (int t = 0; t < 2; ++t)
                op[t * 16] = pack2(acc[2 * t][r], acc[2 * t + 1][r]);
        }
    }

    float asv[4], adv[4];
    #pragma unroll
    for (int nt = 0; nt < 4; ++nt) {
        int n = (nt >> 1) * 32 + 2 * (lane & 15) + (nt & 1);
        asv[nt] = a_src[n];
        adv[nt] = a_dst[n];
    }
    #pragma unroll
    for (int r = 0; r < 4; ++r) {
        float s = 0.f, d = 0.f;
        #pragma unroll
        for (int nt = 0; nt < 4; ++nt) {
            s += acc[nt][r] * asv[nt];
            d += acc[nt][r] * adv[nt];
        }
        s += __shfl_xor(s, 1, 64); s += __shfl_xor(s, 2, 64);
        s += __shfl_xor(s, 4, 64); s += __shfl_xor(s, 8, 64);
        d += __shfl_xor(d, 1, 64); d += __shfl_xor(d, 2, 64);
        d += __shfl_xor(d, 4, 64); d += __shfl_xor(d, 8, 64);
        int node = base + (lane >> 4) * 4 + r;
        if ((lane & 15) == 0 && node < N_NODES) { al[node] = s; ar[node] = d; }
    }
}

// ===== Layer 2 fused single-pass aggregation ================================
__global__ __launch_bounds__(256) void aggr2_csr(
        const int* __restrict__ rowstart, const int* __restrict__ col,
        const float* __restrict__ al, const float* __restrict__ ar,
        const unsigned short* __restrict__ h2b, const float* __restrict__ b2,
        float* __restrict__ out) {
    const int lane = threadIdx.x & 63;
    const int d = blockIdx.x * 4 + (threadIdx.x >> 6);
    if (d >= N_NODES) return;
    const int beg = rowstart[d], end = rowstart[d + 1];
    const float ard = ar[d];

    const int e8 = lane & 7;
    const int g  = lane >> 4;
    const int L  = lane & 15;

    float dsum = 0.f;
    float4 acc = {0.f, 0.f, 0.f, 0.f};

    for (int i = beg; i < end; i += 8) {
        const int e = i + e8;
        const int sv_e = col[e < end ? e : end - 1];
        const float ex = (e < end) ? lrexp(al[sv_e] + ard) : 0.f;
        dsum += ex;
        #pragma unroll
        for (int q = 0; q < 2; ++q) {
            const int slot = q * 4 + g;
            const int   sq = __shfl(sv_e, slot, 64);
            const float wq = __shfl(ex, slot, 64);
            const ushort4 v = *(const ushort4*)&h2b[(size_t)sq * OUTC + L * 4];
            acc.x += wq * bf2f(v.x); acc.y += wq * bf2f(v.y);
            acc.z += wq * bf2f(v.z); acc.w += wq * bf2f(v.w);
        }
    }
    dsum += __shfl_xor(dsum, 1, 64);
    dsum += __shfl_xor(dsum, 2, 64);
    dsum += __shfl_xor(dsum, 4, 64);
    const float inv = 1.f / (dsum + 1e-16f);
    acc.x *= inv; acc.y *= inv; acc.z *= inv; acc.w *= inv;
    #pragma unroll
    for (int o = 16; o < 64; o <<= 1) {
        acc.x += __shfl_xor(acc.x, o, 64);
        acc.y += __shfl_xor(acc.y, o, 64);
        acc.z += __shfl_xor(acc.z, o, 64);
        acc.w += __shfl_xor(acc.w, o, 64);
    }
    if (g == 0) {
        const float4 bb = *(const float4*)&b2[L * 4];
        float4 ov = { acc.x + bb.x, acc.y + bb.y, acc.z + bb.z, acc.w + bb.w };
        *(float4*)&out[(size_t)d * OUTC + L * 4] = ov;
    }
}

extern "C" void kernel_launch(void* const* d_in, const int* in_sizes, int n_in,
                              void* d_out, int out_size, void* d_ws, size_t ws_size,
                              hipStream_t stream) {
    const float* x      = (const float*)d_in[0];
    const int*   ei     = (const int*)  d_in[1];
    const float* W1     = (const float*)d_in[2];
    const float* a_src1 = (const float*)d_in[3];
    const float* a_dst1 = (const float*)d_in[4];
    const float* b1     = (const float*)d_in[5];
    const float* W2     = (const float*)d_in[6];
    const float* a_src2 = (const float*)d_in[7];
    const float* a_dst2 = (const float*)d_in[8];
    const float* b2     = (const float*)d_in[9];
    float* out = (float*)d_out;

    // ---- workspace layout ----
    char* p = (char*)d_ws;
    ushort_t* h1b   = (ushort_t*)p; p += (size_t)N_NODES * HC * 2;   // 25.6 MB
    ushort_t* out1b = (ushort_t*)p; p += (size_t)N_NODES * HC * 2;   // 25.6 MB
    ushort_t* h2b   = (ushort_t*)p; p += (size_t)N_NODES * OUTC * 2; // 6.4 MB
    ushort_t* W1f  = (ushort_t*)p; p += 32768 * 2;                   // 64 KB
    ushort_t* W2f  = (ushort_t*)p; p += 16384 * 2;                   // 32 KB
    float* al1  = (float*)p;  p += (size_t)N_NODES * HEADS * sizeof(float);
    float* ar1  = (float*)p;  p += (size_t)N_NODES * HEADS * sizeof(float);
    float* al2  = (float*)p;  p += (size_t)N_NODES * sizeof(float);
    float* ar2  = (float*)p;  p += (size_t)N_NODES * sizeof(float);
    int* deg      = (int*)p;  p += (size_t)N_NODES * sizeof(int);
    int* inc      = (int*)p;  p += (size_t)N_NODES * sizeof(int);
    int* bsum     = (int*)p;  p += (size_t)NSCANB * sizeof(int);
    int* rowstart = (int*)p;  p += (size_t)(N_NODES + 1) * sizeof(int);
    int* cursor   = (int*)p;  p += (size_t)N_NODES * sizeof(int);
    int* col      = (int*)p;  p += (size_t)E_TOT * sizeof(int);

    // ---- CSR build + weight repack ----
    hipMemsetAsync(deg, 0, (size_t)N_NODES * sizeof(int), stream);
    prep_kernel    <<<(E_TOT + 255)/256, 256, 0, stream>>>(ei, deg, W1, W2, W1f, W2f);
    scan1_kernel   <<<NSCANB, 256, 0, stream>>>(deg, inc, bsum);
    finalize_kernel<<<(N_NODES + 255)/256, 256, 0, stream>>>(inc, bsum, rowstart, cursor);
    scatter_kernel <<<(E_TOT + 255)/256, 256, 0, stream>>>(ei, cursor, col);

    // ---- layer 1 ----
    gemm1_mfma <<<(N_NODES + 63)/64, 256, 0, stream>>>(x, W1f, a_src1, a_dst1, h1b, al1, ar1);
    aggr1_csr  <<<(N_NODES + 3)/4, 256, 0, stream>>>(rowstart, col, al1, ar1, h1b, b1, out1b);

    // ---- layer 2 ----
    gemm2_mfma <<<(N_NODES + 63)/64, 256, 0, stream>>>(out1b, W2f, a_src2, a_dst2, h2b, al2, ar2);
    aggr2_csr  <<<(N_NODES + 3)/4, 256, 0, stream>>>(rowstart, col, al2, ar2, h2b, b2, out);
}